// Round 6
// baseline (640.038 us; speedup 1.0000x reference)
//
#include <hip/hip_runtime.h>
#include <hip/hip_bf16.h>
#include <math.h>

#define NN   6000
#define N2   12000
#define DD   128
#define RR   1000
#define CAP  96
#define CAPR 48
#define MAXN_F 0.996f

typedef short  bf16x8 __attribute__((ext_vector_type(8)));
typedef float  f32x4  __attribute__((ext_vector_type(4)));
typedef unsigned u32x4 __attribute__((ext_vector_type(4)));

// ---------------- module-global scratch ----------------
__device__ int      g_dt[19];
__device__ unsigned g_csri[N2 * CAP];
__device__ int      g_cnt[N2];
__device__ float    g_seq[N2 * 3 * DD];
__device__ unsigned short g_seqb[N2 * 3 * DD];
__device__ unsigned short g_hhb[N2 * 256];
__device__ float    g_es[2][N2];
__device__ float    g_ed[2][N2];
__device__ unsigned short g_ob[(size_t)N2 * 3 * 256];
__device__ float    g_t[N2 * DD];
__device__ float    g_t2[N2 * DD];
// packed weights
__device__ unsigned short g_WgatT[2][256 * DD];
__device__ unsigned short g_WqkvT[768 * DD];
__device__ unsigned short g_WfcT[DD * 256];
__device__ float    g_WhgcT[2][DD * DD];

__device__ __forceinline__ float ldin(const void* p, size_t i, int bf) {
    if (bf) return __uint_as_float(((unsigned)((const unsigned short*)p)[i]) << 16);
    return ((const float*)p)[i];
}
__device__ __forceinline__ unsigned short f2b(float f) {
    unsigned u = __float_as_uint(f);
    u += 0x7FFFu + ((u >> 16) & 1u);
    return (unsigned short)(u >> 16);
}
__device__ __forceinline__ float b2f(unsigned short b) {
    return __uint_as_float(((unsigned)b) << 16);
}
__device__ __forceinline__ float adjval(int c) {   // bf16(1/c), as the dataset quantized it
    return b2f(f2b(1.0f / (float)c));
}

// ---- wave64 shuffle reductions ----
__device__ __forceinline__ float wsum(float v) {
    #pragma unroll
    for (int o = 32; o > 0; o >>= 1) v += __shfl_xor(v, o, 64);
    return v;
}
__device__ __forceinline__ float wmax(float v) {
    #pragma unroll
    for (int o = 32; o > 0; o >>= 1) v = fmaxf(v, __shfl_xor(v, o, 64));
    return v;
}

struct P19 { const void* p[19]; };

// blocks 0..18: dtype detect per input; block 19: local detect of slot 17 + pack g_WhgcT
__global__ void detect_all(P19 ptrs) {
    const int sizes[19] = {768000,768000,128000,128000,36000000,36000000,6000000,6000000,
                           65536,512,512,32768,32768,32768,32768,128,128,32768,256};
    __shared__ int votes[2];
    if (threadIdx.x == 0) { votes[0] = 0; votes[1] = 0; }
    __syncthreads();
    int slot = blockIdx.x < 19 ? blockIdx.x : 17;
    const unsigned* p = (const unsigned*)ptrs.p[slot];
    int nwords = sizes[slot] / 2;
    if (nwords > 0) {
        int nsamp = nwords < 4096 ? nwords : 4096;
        int stride = nwords / nsamp; if (stride < 1) stride = 1;
        for (int s = threadIdx.x; s < nsamp; s += blockDim.x) {
            unsigned lo = p[(size_t)s * stride] & 0xFFFFu;
            if (lo) {
                unsigned e = (lo >> 7) & 0xFFu;
                if (e >= 100u && e <= 140u) atomicAdd(&votes[1], 1);
                else                        atomicAdd(&votes[0], 1);
            }
        }
    }
    __syncthreads();
    int isbf = (votes[1] > votes[0]) ? 1 : 0;
    if (blockIdx.x < 19) {
        if (threadIdx.x == 0) g_dt[blockIdx.x] = isbf;
    } else {
        for (int i = threadIdx.x; i < 32768; i += blockDim.x) {
            int j = i & 127, d = (i >> 7) & 127, l = i >> 14;
            g_WhgcT[l][j * 128 + d] = ldin(ptrs.p[17], i, isbf);
        }
    }
}

// ---------------- wave-local hyperbolic cores (1 wave = 1 node, lane owns d & d+64) ----
__device__ __forceinline__ void bias_wave(const void* hgc_b, int layer, int lane,
                                          float& y0, float& y1, float& y2) {
    float b0 = ldin(hgc_b, (size_t)layer * DD + lane, g_dt[18]);
    float b1 = ldin(hgc_b, (size_t)layer * DD + 64 + lane, g_dt[18]);
    float ss = wsum(b0 * b0 + b1 * b1);
    float nrm = fmaxf(sqrtf(ss), 1e-15f);
    float t = tanhf(nrm);
    float s = t / nrm;
    float vn = t;
    if (t > MAXN_F) { s *= MAXN_F / t; vn = MAXN_F; }
    y0 = s * b0; y1 = s * b1;
    y2 = vn * vn;
}

__device__ __forceinline__ void hgc_lin_w(const float* uw, int layer, int lane,
                                          float y0, float y1, float y2,
                                          float& o0, float& o1) {
    const float* W = g_WhgcT[layer];
    float mv0 = 0.f, mv1 = 0.f;
    #pragma unroll 16
    for (int j = 0; j < DD; j++) {
        float uj = uw[j];
        mv0 = fmaf(W[j * 128 + lane], uj, mv0);
        mv1 = fmaf(W[j * 128 + 64 + lane], uj, mv1);
    }
    float ss2 = wsum(mv0 * mv0 + mv1 * mv1);
    float nm = fmaxf(sqrtf(ss2), 1e-15f);
    float t2 = tanhf(nm);
    float sc = t2 / nm; float xn = t2;
    if (t2 > MAXN_F) { sc *= MAXN_F / t2; xn = MAXN_F; }
    float x0 = sc * mv0, x1 = sc * mv1;
    float x2 = xn * xn;
    float xy = wsum(x0 * y0 + x1 * y1);
    float a = 1.f + 2.f * xy + y2;
    float den = 1.f + 2.f * xy + x2 * y2;
    den = (fabsf(den) < 1e-15f) ? 1e-15f : den;
    float h0 = (a * x0 + (1.f - x2) * y0) / den;
    float h1 = (a * x1 + (1.f - x2) * y1) / den;
    float s3 = wsum(h0 * h0 + h1 * h1);
    float nn = fmaxf(sqrtf(s3), 1e-15f);
    float f = 1.f;
    if (nn > MAXN_F) { f = MAXN_F / nn; nn = MAXN_F; }
    float lg = atanhf(fminf(nn, 1.f - 1e-7f)) / nn;
    o0 = lg * f * h0; o1 = lg * f * h1;
}

__device__ __forceinline__ void hgc_agg_w(const float* tin, int n, int which, int lane,
                                          unsigned* bas, float& o0, float& o1) {
    int c = min(g_cnt[n], CAP);
    const unsigned* idx = &g_csri[(size_t)n * CAP];
    if (lane < c)      bas[lane]      = (idx[lane]      + (unsigned)(which * NN)) * 128u;
    if (64 + lane < c) bas[64 + lane] = (idx[64 + lane] + (unsigned)(which * NN)) * 128u;
    float a0 = 0.f, a1 = 0.f;
    int j = 0;
    for (; j + 4 <= c; j += 4) {
        unsigned b0 = bas[j], b1 = bas[j + 1], b2 = bas[j + 2], b3 = bas[j + 3];
        float v0 = tin[(size_t)b0 + lane], v1 = tin[(size_t)b1 + lane];
        float v2 = tin[(size_t)b2 + lane], v3 = tin[(size_t)b3 + lane];
        float w0 = tin[(size_t)b0 + 64 + lane], w1 = tin[(size_t)b1 + 64 + lane];
        float w2 = tin[(size_t)b2 + 64 + lane], w3 = tin[(size_t)b3 + 64 + lane];
        a0 += (v0 + v1) + (v2 + v3);
        a1 += (w0 + w1) + (w2 + w3);
    }
    for (; j < c; j++) {
        unsigned bb = bas[j];
        a0 += tin[(size_t)bb + lane];
        a1 += tin[(size_t)bb + 64 + lane];
    }
    float sc = (c > 0) ? adjval(c) : 0.f;
    a0 *= sc; a1 *= sc;
    float ss = wsum(a0 * a0 + a1 * a1);
    float nm = fmaxf(sqrtf(ss), 1e-15f);
    float t = tanhf(nm);
    float s1 = t / nm; float xn = t;
    if (t > MAXN_F) { s1 *= MAXN_F / t; xn = MAXN_F; }
    float lg = atanhf(fminf(xn, 1.f - 1e-7f)) / fmaxf(xn, 1e-15f);
    float u0 = fmaxf(lg * s1 * a0, 0.f), u1 = fmaxf(lg * s1 * a1, 0.f);
    float ss2 = wsum(u0 * u0 + u1 * u1);
    float nm2 = fmaxf(sqrtf(ss2), 1e-15f);
    float t2 = tanhf(nm2);
    float s2 = t2 / nm2; float xn2 = t2;
    if (t2 > MAXN_F) { s2 *= MAXN_F / t2; xn2 = MAXN_F; }
    float lg2 = atanhf(fminf(xn2, 1.f - 1e-7f)) / fmaxf(xn2, 1e-15f);
    o0 = lg2 * s2 * u0; o1 = lg2 * s2 * u1;
}

// ---------------- mega front kernel ----------------
__global__ __launch_bounds__(256) void front_mega(P19 in, float* __restrict__ out) {
    int b = blockIdx.x;
    int tid = threadIdx.x;
    int w = tid >> 6, lane = tid & 63;
    int phase, pb;
    if (b < 9000) { pb = b / 3; phase = b - pb * 3; }
    else { phase = 3; pb = b - 9000; }

    if (phase == 0) {
        // Adjacency scan: per-lane zero tests + LDS-atomic compaction (order-free).
        int which = pb >= 1500 ? 1 : 0;
        int row = ((which ? pb - 1500 : pb) << 2) | w;
        const void* A = in.p[4 + which];
        int gn = which * NN + row;
        __shared__ int cnt4[4];
        if (lane == 0) cnt4[w] = 0;
        __syncthreads();
        unsigned* dst = &g_csri[(size_t)gn * CAP];
        if (g_dt[4 + which]) {
            const u32x4* p = (const u32x4*)((const unsigned short*)A + (size_t)row * NN);
            #pragma unroll
            for (int c0 = 0; c0 < 12; c0 += 6) {
                u32x4 v[6];
                #pragma unroll
                for (int u = 0; u < 6; u++) {
                    int idx = (c0 + u) * 64 + lane;
                    if (idx < 750) v[u] = __builtin_nontemporal_load(&p[idx]);
                    else v[u] = (u32x4)(0u);
                }
                #pragma unroll
                for (int u = 0; u < 6; u++) {
                    int idx = (c0 + u) * 64 + lane;
                    #pragma unroll
                    for (int h = 0; h < 4; h++) {
                        unsigned w32 = v[u][h];
                        if (w32) {
                            unsigned lo = w32 & 0xFFFFu, hi = w32 >> 16;
                            if (lo && !(lo & 0x8000u)) {
                                int q = atomicAdd(&cnt4[w], 1);
                                if (q < CAP) dst[q] = (unsigned)(idx * 8 + h * 2);
                            }
                            if (hi && !(hi & 0x8000u)) {
                                int q = atomicAdd(&cnt4[w], 1);
                                if (q < CAP) dst[q] = (unsigned)(idx * 8 + h * 2 + 1);
                            }
                        }
                    }
                }
            }
        } else {
            const f32x4* p = (const f32x4*)((const float*)A + (size_t)row * NN);
            #pragma unroll
            for (int c0 = 0; c0 < 24; c0 += 6) {
                f32x4 v[6];
                #pragma unroll
                for (int u = 0; u < 6; u++) {
                    int idx = (c0 + u) * 64 + lane;
                    if (idx < 1500) v[u] = __builtin_nontemporal_load(&p[idx]);
                    else v[u] = (f32x4)(0.f);
                }
                #pragma unroll
                for (int u = 0; u < 6; u++) {
                    int idx = (c0 + u) * 64 + lane;
                    #pragma unroll
                    for (int h = 0; h < 4; h++) {
                        if (v[u][h] > 0.f) {
                            int q = atomicAdd(&cnt4[w], 1);
                            if (q < CAP) dst[q] = (unsigned)(idx * 4 + h);
                        }
                    }
                }
            }
        }
        __syncthreads();
        if (lane == 0) g_cnt[gn] = min(cnt4[w], CAP);
    } else if (phase == 1) {
        // rel_agg: one wave per node, no barriers (wave-local LDS).
        int n = pb * 4 + w;
        int which = n >= NN ? 1 : 0;
        int row = n - which * NN;
        const void* radj = in.p[6 + which];
        const void* rel  = in.p[2 + which];
        const int bfa = g_dt[6 + which], bfr = g_dt[2 + which];
        __shared__ int rl_list[4][CAPR];
        __shared__ int rl_cs[4];
        if (lane == 0) rl_cs[w] = 0;
        if (bfa) {
            const uint4* p = (const uint4*)((const unsigned short*)radj + (size_t)row * RR);
            #pragma unroll
            for (int rep = 0; rep < 2; rep++) {
                int i = rep * 64 + lane;
                if (i < 125) {
                    uint4 w4 = p[i];
                    unsigned ws4[4] = {w4.x, w4.y, w4.z, w4.w};
                    #pragma unroll
                    for (int h = 0; h < 4; h++) {
                        unsigned lo = ws4[h] & 0xFFFFu, hi = ws4[h] >> 16;
                        if (lo && !(lo & 0x8000u)) { int q = atomicAdd(&rl_cs[w], 1); if (q < CAPR) rl_list[w][q] = i * 8 + h * 2; }
                        if (hi && !(hi & 0x8000u)) { int q = atomicAdd(&rl_cs[w], 1); if (q < CAPR) rl_list[w][q] = i * 8 + h * 2 + 1; }
                    }
                }
            }
        } else {
            const float4* p = (const float4*)((const float*)radj + (size_t)row * RR);
            #pragma unroll
            for (int rep = 0; rep < 4; rep++) {
                int i = rep * 64 + lane;
                if (i < 250) {
                    float4 w4 = p[i];
                    float vs[4] = {w4.x, w4.y, w4.z, w4.w};
                    #pragma unroll
                    for (int h = 0; h < 4; h++)
                        if (vs[h] > 0.f) { int q = atomicAdd(&rl_cs[w], 1); if (q < CAPR) rl_list[w][q] = i * 4 + h; }
                }
            }
        }
        int c = min(rl_cs[w], CAPR);
        float a0 = 0.f, a1 = 0.f;
        for (int j = 0; j < c; j++) {
            int li = rl_list[w][j];
            a0 += ldin(rel, (size_t)li * DD + lane, bfr);
            a1 += ldin(rel, (size_t)li * DD + 64 + lane, bfr);
        }
        float r0 = c ? a0 / (float)c : 0.f;
        float r1 = c ? a1 / (float)c : 0.f;
        out[(size_t)n * 256 + 128 + lane] = r0;
        out[(size_t)n * 256 + 192 + lane] = r1;
        out[(size_t)(2 * NN + n) * 256 + 128 + lane] = r0;
        out[(size_t)(2 * NN + n) * 256 + 192 + lane] = r1;
    } else if (phase == 2) {
        // ent_init: one wave per node, barrier-free.
        int n = pb * 4 + w;
        int which = n >= NN ? 1 : 0;
        int row = n - which * NN;
        __shared__ float us[4][128];
        float y0, y1, y2v;
        bias_wave(in.p[18], 0, lane, y0, y1, y2v);
        float x0 = ldin(in.p[which], (size_t)row * DD + lane, g_dt[which]);
        float x1 = ldin(in.p[which], (size_t)row * DD + 64 + lane, g_dt[which]);
        g_seq[(size_t)n * 384 + lane] = x0;
        g_seq[(size_t)n * 384 + 64 + lane] = x1;
        g_seqb[(size_t)n * 384 + lane] = f2b(x0);
        g_seqb[(size_t)n * 384 + 64 + lane] = f2b(x1);
        float ss = wsum(x0 * x0 + x1 * x1);
        float nrm = fmaxf(sqrtf(ss), 1e-15f);
        float t = tanhf(nrm);
        float scale = t / nrm;
        float hn = t;
        if (t > MAXN_F) { scale *= MAXN_F / t; hn = MAXN_F; }
        float lgx = atanhf(fminf(hn, 1.f - 1e-7f)) / fmaxf(hn, 1e-15f);
        us[w][lane] = lgx * scale * x0;
        us[w][64 + lane] = lgx * scale * x1;
        float o0, o1;
        hgc_lin_w(us[w], 0, lane, y0, y1, y2v, o0, o1);
        g_t[(size_t)n * DD + lane] = o0;
        g_t[(size_t)n * DD + 64 + lane] = o1;
    } else {
        int stride = 128 * 256;
        int base = pb * 256 + tid;
        const int b8 = g_dt[8], b11 = g_dt[11], b12 = g_dt[12], b13 = g_dt[13],
                  b14 = g_dt[14];
        for (int i = base; i < 65536; i += stride) {
            int e = i & 127, d = (i >> 7) & 127, h = (i >> 14) & 1, l = (i >> 15) & 1;
            g_WgatT[l][(h * 128 + e) * DD + d] = f2b(ldin(in.p[8], i, b8));
        }
        for (int i = base; i < 32768; i += stride) {
            int d = i >> 8, e = i & 255;
            g_WqkvT[(size_t)e * DD + d]         = f2b(ldin(in.p[11], i, b11));
            g_WqkvT[(size_t)(256 + e) * DD + d] = f2b(ldin(in.p[12], i, b12));
            g_WqkvT[(size_t)(512 + e) * DD + d] = f2b(ldin(in.p[13], i, b13));
        }
        for (int i = base; i < 32768; i += stride) {
            int e = i >> 7, dd = i & 127;
            g_WfcT[dd * 256 + e] = f2b(ldin(in.p[14], i, b14));
        }
    }
}

// ---------------- GAT GEMM with fused scores epilogue (GEMM-only kernel) ----------------
__global__ __launch_bounds__(256) void gemm_scores(P19 in, int layer) {
    __shared__ __align__(16) unsigned short As[16 * 128 * 8];
    __shared__ __align__(16) unsigned short Bs[16 * 128 * 8];
    int tid = threadIdx.x;
    int gb = blockIdx.x;
    int bm = (gb >> 1) * 128, bn = (gb & 1) * 128;
    const unsigned short* A = g_seqb + layer * 128;
    const int lda = 384;
    const unsigned short* Bt = g_WgatT[layer];
    const int M = N2;
    int lane = tid & 63, w = tid >> 6;
    int q = lane >> 4, ln = lane & 15;
    f32x4 acc[8][2] = {};
    {
        #pragma unroll
        for (int i = 0; i < 8; i++) {
            int combo = w * 8 + i;
            int c = combo >> 1, half = combo & 1;
            int r = half * 64 + lane;
            int gm = bm + r; if (gm >= M) gm = M - 1;
            *(uint4*)&As[(c * 128 + r) * 8] = *(const uint4*)(A + (size_t)gm * lda + c * 8);
            *(uint4*)&Bs[(c * 128 + r) * 8] = *(const uint4*)(Bt + (size_t)(bn + r) * DD + c * 8);
        }
        __syncthreads();
        #pragma unroll
        for (int s = 0; s < 4; s++) {
            bf16x8 bf0 = *(const bf16x8*)&Bs[((s * 4 + q) * 128 + w * 32 + ln) * 8];
            bf16x8 bf1 = *(const bf16x8*)&Bs[((s * 4 + q) * 128 + w * 32 + 16 + ln) * 8];
            #pragma unroll
            for (int mt = 0; mt < 8; mt++) {
                bf16x8 af = *(const bf16x8*)&As[((s * 4 + q) * 128 + mt * 16 + ln) * 8];
                acc[mt][0] = __builtin_amdgcn_mfma_f32_16x16x32_bf16(af, bf0, acc[mt][0], 0, 0, 0);
                acc[mt][1] = __builtin_amdgcn_mfma_f32_16x16x32_bf16(af, bf1, acc[mt][1], 0, 0, 0);
            }
        }
    }
    #pragma unroll
    for (int mt = 0; mt < 8; mt++) {
        #pragma unroll
        for (int nt = 0; nt < 2; nt++) {
            int gcol = bn + w * 32 + nt * 16 + ln;
            #pragma unroll
            for (int r = 0; r < 4; r++) {
                int grow = bm + mt * 16 + q * 4 + r;
                if (grow < M)
                    g_hhb[(size_t)grow * 256 + gcol] = f2b(acc[mt][nt][r]);
            }
        }
    }
    const int head = bn >> 7;
    const int bfs = g_dt[9], bfd = g_dt[10];
    size_t abase = ((size_t)layer * 2 + head) * DD;
    int c0 = w * 32 + ln, c1 = w * 32 + 16 + ln;
    float a0s = ldin(in.p[9],  abase + c0, bfs), a1s = ldin(in.p[9],  abase + c1, bfs);
    float a0d = ldin(in.p[10], abase + c0, bfd), a1d = ldin(in.p[10], abase + c1, bfd);
    __syncthreads();
    float* pS = (float*)As;
    float* pD = pS + 512;
    #pragma unroll
    for (int mt = 0; mt < 8; mt++) {
        #pragma unroll
        for (int r = 0; r < 4; r++) {
            int row = mt * 16 + q * 4 + r;
            float ps = acc[mt][0][r] * a0s + acc[mt][1][r] * a1s;
            float pd = acc[mt][0][r] * a0d + acc[mt][1][r] * a1d;
            #pragma unroll
            for (int o = 1; o < 16; o <<= 1) {
                ps += __shfl_xor(ps, o, 64);
                pd += __shfl_xor(pd, o, 64);
            }
            if (ln == 0) { pS[w * 128 + row] = ps; pD[w * 128 + row] = pd; }
        }
    }
    __syncthreads();
    if (tid < 128) {
        int grow = bm + tid;
        if (grow < M) {
            g_es[head][grow] = pS[tid] + pS[128 + tid] + pS[256 + tid] + pS[384 + tid];
            g_ed[head][grow] = pD[tid] + pD[128 + tid] + pD[256 + tid] + pD[384 + tid];
        }
    }
}

// ---------------- GAT attention: wave-per-node, zero barriers ----------------
__global__ __launch_bounds__(256) void gat_attn(int layer) {
    int tid = threadIdx.x;
    int w = tid >> 6, lane = tid & 63;
    int n = blockIdx.x * 4 + w;
    int which = n >= NN ? 1 : 0;
    int c = min(g_cnt[n], CAP);
    __shared__ unsigned bas[4][CAP];
    __shared__ float w0s[4][CAP], w1s[4][CAP];
    float es0 = g_es[0][n], es1 = g_es[1][n];
    float e0a = -1e30f, e1a = -1e30f, e0b = -1e30f, e1b = -1e30f;
    if (lane < c) {
        int gI = (int)g_csri[(size_t)n * CAP + lane] + which * NN;
        bas[w][lane] = (unsigned)gI * 128u;
        e0a = es0 + g_ed[0][gI]; e0a = e0a > 0.f ? e0a : 0.2f * e0a;
        e1a = es1 + g_ed[1][gI]; e1a = e1a > 0.f ? e1a : 0.2f * e1a;
    }
    if (64 + lane < c) {
        int gI = (int)g_csri[(size_t)n * CAP + 64 + lane] + which * NN;
        bas[w][64 + lane] = (unsigned)gI * 128u;
        e0b = es0 + g_ed[0][gI]; e0b = e0b > 0.f ? e0b : 0.2f * e0b;
        e1b = es1 + g_ed[1][gI]; e1b = e1b > 0.f ? e1b : 0.2f * e1b;
    }
    float m0 = wmax(fmaxf(e0a, e0b));
    float m1 = wmax(fmaxf(e1a, e1b));
    float x0a = (lane < c) ? expf(e0a - m0) : 0.f;
    float x1a = (lane < c) ? expf(e1a - m1) : 0.f;
    float x0b = (64 + lane < c) ? expf(e0b - m0) : 0.f;
    float x1b = (64 + lane < c) ? expf(e1b - m1) : 0.f;
    float s0 = wsum(x0a + x0b), s1 = wsum(x1a + x1b);
    float r0 = 1.f / fmaxf(s0, 1e-30f), r1 = 1.f / fmaxf(s1, 1e-30f);
    if (lane < c)      { w0s[w][lane] = x0a * r0;      w1s[w][lane] = x1a * r1; }
    if (64 + lane < c) { w0s[w][64 + lane] = x0b * r0; w1s[w][64 + lane] = x1b * r1; }
    const unsigned* hh32 = (const unsigned*)g_hhb;
    float aLe = 0.f, aLo = 0.f, aHe = 0.f, aHo = 0.f;
    #pragma unroll 4
    for (int j = 0; j < c; j++) {
        unsigned bb = bas[w][j];
        unsigned vlo = hh32[(size_t)bb + lane];
        unsigned vhi = hh32[(size_t)bb + 64 + lane];
        float g0 = w0s[w][j], g1 = w1s[w][j];
        aLe = fmaf(g0, b2f((unsigned short)(vlo & 0xFFFFu)), aLe);
        aLo = fmaf(g0, b2f((unsigned short)(vlo >> 16)), aLo);
        aHe = fmaf(g1, b2f((unsigned short)(vhi & 0xFFFFu)), aHe);
        aHo = fmaf(g1, b2f((unsigned short)(vhi >> 16)), aHo);
    }
    float o0 = (c > 0) ? 0.5f * (aLe + aHe) : 0.f;
    float o1 = (c > 0) ? 0.5f * (aLo + aHo) : 0.f;
    o0 = o0 > 0.f ? o0 : expm1f(o0);
    o1 = o1 > 0.f ? o1 : expm1f(o1);
    float ss = wsum(o0 * o0 + o1 * o1);
    float rn = 1.f / fmaxf(sqrtf(ss), 1e-12f);
    o0 *= rn; o1 *= rn;
    size_t base = (size_t)n * 384 + (layer + 1) * 128 + 2 * lane;
    g_seq[base] = o0; g_seq[base + 1] = o1;
    *(unsigned*)&g_seqb[base] = (unsigned)f2b(o0) | ((unsigned)f2b(o1) << 16);
}

// ---------------- fused qkv-GEMM + MHA ∥ hgc_mid ----------------
// b%3==0: qkv+MHA for 8 nodes (pb=b/3 in [0,1500)); else hgc_mid 4 nodes
// (pb = (b/3)*2 + b%3-1 in [0,3000)).
// qkv GEMM: 24 rows (pad 32) x 768 cols, K=128. A staged k-major in LDS;
// B fragments streamed directly from L2-resident g_WqkvT (196KB, shared by all
// blocks). Result kept in LDS (bf16, same f2b rounding as old global path);
// MHA consumes in-block. g_qkvb is never materialized (-110MB HBM).
__global__ __launch_bounds__(256) void qkv_mid(const void* __restrict__ hgc_b) {
    int b = blockIdx.x;
    int tid = threadIdx.x;
    int w = tid >> 6, lane = tid & 63;
    int grp = b / 3, r3 = b - grp * 3;
    if (r3 == 0) {
        int pb = grp;
        __shared__ __align__(16) unsigned short As[16 * 32 * 8];   // 8KB, [c][r] k-major
        __shared__ __align__(16) unsigned short Qs[8 * 2304];       // 36.9KB qkv result
        int q = lane >> 4, ln = lane & 15;
        #pragma unroll
        for (int i = 0; i < 2; i++) {
            int slot = i * 256 + tid;          // 512 slots = [c16][r32]
            int c = slot >> 5, r = slot & 31;
            int rr = r < 24 ? r : 23;
            int nl = rr / 3, l = rr - nl * 3;
            int n = pb * 8 + nl;
            *(uint4*)&As[slot * 8] = *(const uint4*)(g_seqb + (size_t)n * 384 + l * 128 + c * 8);
        }
        __syncthreads();
        f32x4 acc[2][12] = {};
        const unsigned short* Bt = g_WqkvT;
        int colbase = w * 192;
        #pragma unroll
        for (int s = 0; s < 4; s++) {
            bf16x8 af0 = *(const bf16x8*)&As[((s * 4 + q) * 32 + ln) * 8];
            bf16x8 af1 = *(const bf16x8*)&As[((s * 4 + q) * 32 + 16 + ln) * 8];
            #pragma unroll
            for (int nt = 0; nt < 12; nt++) {
                int col = colbase + nt * 16 + ln;
                bf16x8 bf = *(const bf16x8*)(Bt + (size_t)col * 128 + (s * 4 + q) * 8);
                acc[0][nt] = __builtin_amdgcn_mfma_f32_16x16x32_bf16(af0, bf, acc[0][nt], 0, 0, 0);
                acc[1][nt] = __builtin_amdgcn_mfma_f32_16x16x32_bf16(af1, bf, acc[1][nt], 0, 0, 0);
            }
        }
        #pragma unroll
        for (int mt = 0; mt < 2; mt++) {
            #pragma unroll
            for (int nt = 0; nt < 12; nt++) {
                int col = colbase + nt * 16 + ln;
                #pragma unroll
                for (int r = 0; r < 4; r++) {
                    int row = mt * 16 + q * 4 + r;
                    if (row < 24) {
                        int nl = row / 3, l = row - nl * 3;
                        Qs[nl * 2304 + l * 768 + col] = f2b(acc[mt][nt][r]);
                    }
                }
            }
        }
        __syncthreads();
        // MHA: 2 nodes per wave; lane owns dims d0..d0+3 of 256 (lane<32 -> head 0)
        int d0 = lane * 4;
        #pragma unroll
        for (int t = 0; t < 2; t++) {
            int nl = w * 2 + t;
            int n = pb * 8 + nl;
            const unsigned short* rowp = &Qs[nl * 2304];
            float qf[3][4], kf[3][4], vf[3][4];
            #pragma unroll
            for (int l = 0; l < 3; l++) {
                uint2 qv = *(const uint2*)(rowp + l * 768 + d0);
                uint2 kv = *(const uint2*)(rowp + l * 768 + 256 + d0);
                uint2 vv = *(const uint2*)(rowp + l * 768 + 512 + d0);
                qf[l][0] = b2f((unsigned short)(qv.x & 0xFFFFu)); qf[l][1] = b2f((unsigned short)(qv.x >> 16));
                qf[l][2] = b2f((unsigned short)(qv.y & 0xFFFFu)); qf[l][3] = b2f((unsigned short)(qv.y >> 16));
                kf[l][0] = b2f((unsigned short)(kv.x & 0xFFFFu)); kf[l][1] = b2f((unsigned short)(kv.x >> 16));
                kf[l][2] = b2f((unsigned short)(kv.y & 0xFFFFu)); kf[l][3] = b2f((unsigned short)(kv.y >> 16));
                vf[l][0] = b2f((unsigned short)(vv.x & 0xFFFFu)); vf[l][1] = b2f((unsigned short)(vv.x >> 16));
                vf[l][2] = b2f((unsigned short)(vv.y & 0xFFFFu)); vf[l][3] = b2f((unsigned short)(vv.y >> 16));
            }
            float att[3][3];
            #pragma unroll
            for (int l = 0; l < 3; l++) {
                #pragma unroll
                for (int m = 0; m < 3; m++) {
                    float p = 0.f;
                    #pragma unroll
                    for (int i = 0; i < 4; i++) p = fmaf(qf[l][i], kf[m][i], p);
                    #pragma unroll
                    for (int o = 16; o > 0; o >>= 1) p += __shfl_xor(p, o, 64);
                    att[l][m] = p * 0.08838834764831845f;
                }
            }
            #pragma unroll
            for (int l = 0; l < 3; l++) {
                float mx = fmaxf(att[l][0], fmaxf(att[l][1], att[l][2]));
                float e0 = expf(att[l][0] - mx), e1 = expf(att[l][1] - mx), e2 = expf(att[l][2] - mx);
                float s = 1.f / fmaxf(e0 + e1 + e2, 1e-30f);
                att[l][0] = e0 * s; att[l][1] = e1 * s; att[l][2] = e2 * s;
            }
            unsigned short* orow = g_ob + (size_t)n * 768;
            #pragma unroll
            for (int l = 0; l < 3; l++) {
                float o[4];
                #pragma unroll
                for (int i = 0; i < 4; i++)
                    o[i] = att[l][0] * vf[0][i] + att[l][1] * vf[1][i] + att[l][2] * vf[2][i];
                uint2 pk;
                pk.x = (unsigned)f2b(o[0]) | ((unsigned)f2b(o[1]) << 16);
                pk.y = (unsigned)f2b(o[2]) | ((unsigned)f2b(o[3]) << 16);
                *(uint2*)(orow + l * 256 + d0) = pk;
            }
        }
    } else {
        int pb = grp * 2 + (r3 - 1);
        int n = pb * 4 + w;
        int which = n >= NN ? 1 : 0;
        __shared__ unsigned bas[4][CAP];
        __shared__ float us[4][128];
        float y0, y1, y2v;
        bias_wave(hgc_b, 1, lane, y0, y1, y2v);
        float u0, u1;
        hgc_agg_w(g_t, n, which, lane, bas[w], u0, u1);
        us[w][lane] = u0; us[w][64 + lane] = u1;
        float o0, o1;
        hgc_lin_w(us[w], 1, lane, y0, y1, y2v, o0, o1);
        g_t2[(size_t)n * DD + lane] = o0;
        g_t2[(size_t)n * DD + 64 + lane] = o1;
    }
}

// ---------------- fused fc-GEMM + residual + LayerNorm + out ∥ hgc_fin ----------------
// blocks [0,300): 40 nodes each (120 rows, pad to 128), K=256;
// blocks [300,3300): hgc_fin 4 nodes each.
__global__ __launch_bounds__(256) void fc_ln_fin(const void* __restrict__ g, const void* __restrict__ bb_,
                                                 const void* __restrict__ e0, const void* __restrict__ e1,
                                                 float* __restrict__ out) {
    int blk = blockIdx.x;
    int tid = threadIdx.x;
    int w = tid >> 6, lane = tid & 63;
    if (blk < 300) {
        __shared__ __align__(16) unsigned short SM[2 * 16 * 128 * 8];  // 64KB
        __shared__ float muA[128], rsA[128];
        unsigned short* As = SM;
        unsigned short* Bs = SM + 16 * 128 * 8;
        int q = lane >> 4, ln = lane & 15;
        int bm = blk * 120;
        f32x4 acc[8][2] = {};
        for (int k0 = 0; k0 < 256; k0 += 128) {
            if (k0 > 0) __syncthreads();
            #pragma unroll
            for (int i = 0; i < 8; i++) {
                int combo = w * 8 + i;
                int c = combo >> 1, half = combo & 1;
                int r = half * 64 + lane;
                int gm = bm + (r < 120 ? r : 119);
                *(uint4*)&As[(c * 128 + r) * 8] = *(const uint4*)(g_ob + (size_t)gm * 256 + k0 + c * 8);
                *(uint4*)&Bs[(c * 128 + r) * 8] = *(const uint4*)(g_WfcT + (size_t)r * 256 + k0 + c * 8);
            }
            __syncthreads();
            #pragma unroll
            for (int s = 0; s < 4; s++) {
                bf16x8 bf0 = *(const bf16x8*)&Bs[((s * 4 + q) * 128 + w * 32 + ln) * 8];
                bf16x8 bf1 = *(const bf16x8*)&Bs[((s * 4 + q) * 128 + w * 32 + 16 + ln) * 8];
                #pragma unroll
                for (int mt = 0; mt < 8; mt++) {
                    bf16x8 af = *(const bf16x8*)&As[((s * 4 + q) * 128 + mt * 16 + ln) * 8];
                    acc[mt][0] = __builtin_amdgcn_mfma_f32_16x16x32_bf16(af, bf0, acc[mt][0], 0, 0, 0);
                    acc[mt][1] = __builtin_amdgcn_mfma_f32_16x16x32_bf16(af, bf1, acc[mt][1], 0, 0, 0);
                }
            }
        }
        __syncthreads();                      // LDS now reusable
        // add residual in-place
        #pragma unroll
        for (int mt = 0; mt < 8; mt++) {
            #pragma unroll
            for (int nt = 0; nt < 2; nt++) {
                int col = w * 32 + nt * 16 + ln;
                #pragma unroll
                for (int r = 0; r < 4; r++) {
                    int row = mt * 16 + q * 4 + r;
                    int gm = bm + (row < 120 ? row : 119);
                    acc[mt][nt][r] += g_seq[(size_t)gm * 128 + col];
                }
            }
        }
        // per-row sum/sumsq: wave partials -> LDS -> per-row mu/rstd
        float* part = (float*)SM;             // [8][128]: w*2 {sum}, w*2+1 {sumsq}
        #pragma unroll
        for (int mt = 0; mt < 8; mt++) {
            #pragma unroll
            for (int r = 0; r < 4; r++) {
                int row = mt * 16 + q * 4 + r;
                float s = acc[mt][0][r] + acc[mt][1][r];
                float ss = acc[mt][0][r] * acc[mt][0][r] + acc[mt][1][r] * acc[mt][1][r];
                #pragma unroll
                for (int o = 1; o < 16; o <<= 1) {
                    s  += __shfl_xor(s, o, 64);
                    ss += __shfl_xor(ss, o, 64);
                }
                if (ln == 0) { part[(w * 2) * 128 + row] = s; part[(w * 2 + 1) * 128 + row] = ss; }
            }
        }
        __syncthreads();
        if (tid < 128) {
            float s  = part[0 * 128 + tid] + part[2 * 128 + tid] + part[4 * 128 + tid] + part[6 * 128 + tid];
            float ss = part[1 * 128 + tid] + part[3 * 128 + tid] + part[5 * 128 + tid] + part[7 * 128 + tid];
            float mu = s / 128.f;
            muA[tid] = mu;
            rsA[tid] = rsqrtf(ss / 128.f - mu * mu + 1e-6f);
        }
        __syncthreads();
        float* fcn = (float*)SM;              // [128][128] normalized values
        #pragma unroll
        for (int mt = 0; mt < 8; mt++) {
            #pragma unroll
            for (int nt = 0; nt < 2; nt++) {
                int col = w * 32 + nt * 16 + ln;
                #pragma unroll
                for (int r = 0; r < 4; r++) {
                    int row = mt * 16 + q * 4 + r;
                    fcn[row * 128 + col] = (acc[mt][nt][r] - muA[row]) * rsA[row];
                }
            }
        }
        __syncthreads();
        const int bg = g_dt[15], bb = g_dt[16];
        for (int i = tid; i < 40 * 128; i += 256) {
            int nl = i >> 7, d = i & 127;
            int n = blk * 40 + nl;
            float v = (fcn[(nl * 3) * 128 + d] + fcn[(nl * 3 + 1) * 128 + d] + fcn[(nl * 3 + 2) * 128 + d]) / 3.f;
            out[(size_t)n * 256 + d] = ldin(g, d, bg) * v + ldin(bb_, d, bb);
        }
    } else {
        int n = (blk - 300) * 4 + w;
        int which = n >= NN ? 1 : 0;
        __shared__ unsigned bas[4][CAP];
        float u0, u1;
        hgc_agg_w(g_t2, n, which, lane, bas[w], u0, u1);
        float ev0 = ldin(which ? e1 : e0, (size_t)(n - which * NN) * DD + lane, g_dt[which]);
        float ev1 = ldin(which ? e1 : e0, (size_t)(n - which * NN) * DD + 64 + lane, g_dt[which]);
        out[(size_t)(2 * NN + n) * 256 + lane]      = ev0 + u0;
        out[(size_t)(2 * NN + n) * 256 + 64 + lane] = ev1 + u1;
    }
}

extern "C" void kernel_launch(void* const* d_in, const int* in_sizes, int n_in,
                              void* d_out, int out_size, void* d_ws, size_t ws_size,
                              hipStream_t stream) {
    const void* ln_g = d_in[15];
    const void* ln_b = d_in[16];
    const void* hgc_b = d_in[18];

    float* out = (float*)d_out;

    P19 ptrs;
    for (int i = 0; i < 19; i++) ptrs.p[i] = d_in[i];
    detect_all<<<20, 1024, 0, stream>>>(ptrs);

    front_mega<<<9128, 256, 0, stream>>>(ptrs, out);

    gemm_scores<<<188, 256, 0, stream>>>(ptrs, 0);
    gat_attn<<<3000, 256, 0, stream>>>(0);
    gemm_scores<<<188, 256, 0, stream>>>(ptrs, 1);
    gat_attn<<<3000, 256, 0, stream>>>(1);

    qkv_mid<<<4500, 256, 0, stream>>>(hgc_b);
    fc_ln_fin<<<3300, 256, 0, stream>>>(ln_g, ln_b, d_in[0], d_in[1], out);
}

// Round 7
// 595.798 us; speedup vs baseline: 1.0743x; 1.0743x over previous
//
#include <hip/hip_runtime.h>
#include <hip/hip_bf16.h>
#include <math.h>

#define NN   6000
#define N2   12000
#define DD   128
#define RR   1000
#define CAP  96
#define CAPR 48
#define MAXN_F 0.996f

typedef short  bf16x8 __attribute__((ext_vector_type(8)));
typedef float  f32x4  __attribute__((ext_vector_type(4)));
typedef unsigned u32x4 __attribute__((ext_vector_type(4)));

// ---------------- module-global scratch ----------------
__device__ int      g_dt[19];
__device__ unsigned g_csri[N2 * CAP];
__device__ int      g_cnt[N2];
__device__ float    g_seq[N2 * 3 * DD];
__device__ unsigned short g_seqb[3 * N2 * DD];   // layer planes: [l][n][d]
__device__ unsigned short g_hhb[N2 * 256];
__device__ float    g_es[2][N2];
__device__ float    g_ed[2][N2];
__device__ unsigned short g_qkvb[(size_t)N2 * 3 * 768];
__device__ unsigned short g_ob[(size_t)N2 * 3 * 256];
__device__ float    g_fc[N2 * 3 * DD];
__device__ float    g_t[N2 * DD];
__device__ float    g_t2[N2 * DD];
// packed weights
__device__ unsigned short g_WgatT[2][256 * DD];
__device__ unsigned short g_WqkvT[768 * DD];
__device__ unsigned short g_WfcT[DD * 256];
__device__ float    g_WhgcT[2][DD * DD];

__device__ __forceinline__ float ldin(const void* p, size_t i, int bf) {
    if (bf) return __uint_as_float(((unsigned)((const unsigned short*)p)[i]) << 16);
    return ((const float*)p)[i];
}
__device__ __forceinline__ unsigned short f2b(float f) {
    unsigned u = __float_as_uint(f);
    u += 0x7FFFu + ((u >> 16) & 1u);
    return (unsigned short)(u >> 16);
}
__device__ __forceinline__ float b2f(unsigned short b) {
    return __uint_as_float(((unsigned)b) << 16);
}
__device__ __forceinline__ float adjval(int c) {   // bf16(1/c), as the dataset quantized it
    return b2f(f2b(1.0f / (float)c));
}

// ---- wave64 shuffle reductions ----
__device__ __forceinline__ float wsum(float v) {
    #pragma unroll
    for (int o = 32; o > 0; o >>= 1) v += __shfl_xor(v, o, 64);
    return v;
}
__device__ __forceinline__ float wmax(float v) {
    #pragma unroll
    for (int o = 32; o > 0; o >>= 1) v = fmaxf(v, __shfl_xor(v, o, 64));
    return v;
}

struct P19 { const void* p[19]; };

// blocks 0..18: dtype detect per input; block 19: local detect of slot 17 + pack g_WhgcT
__global__ void detect_all(P19 ptrs) {
    const int sizes[19] = {768000,768000,128000,128000,36000000,36000000,6000000,6000000,
                           65536,512,512,32768,32768,32768,32768,128,128,32768,256};
    __shared__ int votes[2];
    if (threadIdx.x == 0) { votes[0] = 0; votes[1] = 0; }
    __syncthreads();
    int slot = blockIdx.x < 19 ? blockIdx.x : 17;
    const unsigned* p = (const unsigned*)ptrs.p[slot];
    int nwords = sizes[slot] / 2;
    if (nwords > 0) {
        int nsamp = nwords < 4096 ? nwords : 4096;
        int stride = nwords / nsamp; if (stride < 1) stride = 1;
        for (int s = threadIdx.x; s < nsamp; s += blockDim.x) {
            unsigned lo = p[(size_t)s * stride] & 0xFFFFu;
            if (lo) {
                unsigned e = (lo >> 7) & 0xFFu;
                if (e >= 100u && e <= 140u) atomicAdd(&votes[1], 1);
                else                        atomicAdd(&votes[0], 1);
            }
        }
    }
    __syncthreads();
    int isbf = (votes[1] > votes[0]) ? 1 : 0;
    if (blockIdx.x < 19) {
        if (threadIdx.x == 0) g_dt[blockIdx.x] = isbf;
    } else {
        for (int i = threadIdx.x; i < 32768; i += blockDim.x) {
            int j = i & 127, d = (i >> 7) & 127, l = i >> 14;
            g_WhgcT[l][j * 128 + d] = ldin(ptrs.p[17], i, isbf);
        }
    }
}

// ---------------- wave-local hyperbolic cores (1 wave = 1 node, lane owns d & d+64) ----
__device__ __forceinline__ void bias_wave(const void* hgc_b, int layer, int lane,
                                          float& y0, float& y1, float& y2) {
    float b0 = ldin(hgc_b, (size_t)layer * DD + lane, g_dt[18]);
    float b1 = ldin(hgc_b, (size_t)layer * DD + 64 + lane, g_dt[18]);
    float ss = wsum(b0 * b0 + b1 * b1);
    float nrm = fmaxf(sqrtf(ss), 1e-15f);
    float t = tanhf(nrm);
    float s = t / nrm;
    float vn = t;
    if (t > MAXN_F) { s *= MAXN_F / t; vn = MAXN_F; }
    y0 = s * b0; y1 = s * b1;
    y2 = vn * vn;
}

__device__ __forceinline__ void hgc_lin_w(const float* uw, int layer, int lane,
                                          float y0, float y1, float y2,
                                          float& o0, float& o1) {
    const float* W = g_WhgcT[layer];
    float mv0 = 0.f, mv1 = 0.f;
    #pragma unroll 16
    for (int j = 0; j < DD; j++) {
        float uj = uw[j];
        mv0 = fmaf(W[j * 128 + lane], uj, mv0);
        mv1 = fmaf(W[j * 128 + 64 + lane], uj, mv1);
    }
    float ss2 = wsum(mv0 * mv0 + mv1 * mv1);
    float nm = fmaxf(sqrtf(ss2), 1e-15f);
    float t2 = tanhf(nm);
    float sc = t2 / nm; float xn = t2;
    if (t2 > MAXN_F) { sc *= MAXN_F / t2; xn = MAXN_F; }
    float x0 = sc * mv0, x1 = sc * mv1;
    float x2 = xn * xn;
    float xy = wsum(x0 * y0 + x1 * y1);
    float a = 1.f + 2.f * xy + y2;
    float den = 1.f + 2.f * xy + x2 * y2;
    den = (fabsf(den) < 1e-15f) ? 1e-15f : den;
    float h0 = (a * x0 + (1.f - x2) * y0) / den;
    float h1 = (a * x1 + (1.f - x2) * y1) / den;
    float s3 = wsum(h0 * h0 + h1 * h1);
    float nn = fmaxf(sqrtf(s3), 1e-15f);
    float f = 1.f;
    if (nn > MAXN_F) { f = MAXN_F / nn; nn = MAXN_F; }
    float lg = atanhf(fminf(nn, 1.f - 1e-7f)) / nn;
    o0 = lg * f * h0; o1 = lg * f * h1;
}

__device__ __forceinline__ void hgc_agg_w(const float* tin, int n, int which, int lane,
                                          unsigned* bas, float& o0, float& o1) {
    int c = min(g_cnt[n], CAP);
    const unsigned* idx = &g_csri[(size_t)n * CAP];
    if (lane < c)      bas[lane]      = (idx[lane]      + (unsigned)(which * NN)) * 128u;
    if (64 + lane < c) bas[64 + lane] = (idx[64 + lane] + (unsigned)(which * NN)) * 128u;
    float a0 = 0.f, a1 = 0.f;
    int j = 0;
    for (; j + 4 <= c; j += 4) {
        unsigned b0 = bas[j], b1 = bas[j + 1], b2 = bas[j + 2], b3 = bas[j + 3];
        float v0 = tin[(size_t)b0 + lane], v1 = tin[(size_t)b1 + lane];
        float v2 = tin[(size_t)b2 + lane], v3 = tin[(size_t)b3 + lane];
        float w0 = tin[(size_t)b0 + 64 + lane], w1 = tin[(size_t)b1 + 64 + lane];
        float w2 = tin[(size_t)b2 + 64 + lane], w3 = tin[(size_t)b3 + 64 + lane];
        a0 += (v0 + v1) + (v2 + v3);
        a1 += (w0 + w1) + (w2 + w3);
    }
    for (; j < c; j++) {
        unsigned bb = bas[j];
        a0 += tin[(size_t)bb + lane];
        a1 += tin[(size_t)bb + 64 + lane];
    }
    float sc = (c > 0) ? adjval(c) : 0.f;
    a0 *= sc; a1 *= sc;
    float ss = wsum(a0 * a0 + a1 * a1);
    float nm = fmaxf(sqrtf(ss), 1e-15f);
    float t = tanhf(nm);
    float s1 = t / nm; float xn = t;
    if (t > MAXN_F) { s1 *= MAXN_F / t; xn = MAXN_F; }
    float lg = atanhf(fminf(xn, 1.f - 1e-7f)) / fmaxf(xn, 1e-15f);
    float u0 = fmaxf(lg * s1 * a0, 0.f), u1 = fmaxf(lg * s1 * a1, 0.f);
    float ss2 = wsum(u0 * u0 + u1 * u1);
    float nm2 = fmaxf(sqrtf(ss2), 1e-15f);
    float t2 = tanhf(nm2);
    float s2 = t2 / nm2; float xn2 = t2;
    if (t2 > MAXN_F) { s2 *= MAXN_F / t2; xn2 = MAXN_F; }
    float lg2 = atanhf(fminf(xn2, 1.f - 1e-7f)) / fmaxf(xn2, 1e-15f);
    o0 = lg2 * s2 * u0; o1 = lg2 * s2 * u1;
}

// ---------------- mega front kernel ----------------
__global__ __launch_bounds__(256) void front_mega(P19 in, float* __restrict__ out) {
    int b = blockIdx.x;
    int tid = threadIdx.x;
    int w = tid >> 6, lane = tid & 63;
    int phase, pb;
    if (b < 9000) { pb = b / 3; phase = b - pb * 3; }
    else { phase = 3; pb = b - 9000; }

    if (phase == 0) {
        // Adjacency scan: per-lane zero tests + LDS-atomic compaction (order-free).
        int which = pb >= 1500 ? 1 : 0;
        int row = ((which ? pb - 1500 : pb) << 2) | w;
        const void* A = in.p[4 + which];
        int gn = which * NN + row;
        __shared__ int cnt4[4];
        if (lane == 0) cnt4[w] = 0;
        __syncthreads();
        unsigned* dst = &g_csri[(size_t)gn * CAP];
        if (g_dt[4 + which]) {
            const u32x4* p = (const u32x4*)((const unsigned short*)A + (size_t)row * NN);
            #pragma unroll
            for (int c0 = 0; c0 < 12; c0 += 6) {
                u32x4 v[6];
                #pragma unroll
                for (int u = 0; u < 6; u++) {
                    int idx = (c0 + u) * 64 + lane;
                    if (idx < 750) v[u] = __builtin_nontemporal_load(&p[idx]);
                    else v[u] = (u32x4)(0u);
                }
                #pragma unroll
                for (int u = 0; u < 6; u++) {
                    int idx = (c0 + u) * 64 + lane;
                    #pragma unroll
                    for (int h = 0; h < 4; h++) {
                        unsigned w32 = v[u][h];
                        if (w32) {
                            unsigned lo = w32 & 0xFFFFu, hi = w32 >> 16;
                            if (lo && !(lo & 0x8000u)) {
                                int q = atomicAdd(&cnt4[w], 1);
                                if (q < CAP) dst[q] = (unsigned)(idx * 8 + h * 2);
                            }
                            if (hi && !(hi & 0x8000u)) {
                                int q = atomicAdd(&cnt4[w], 1);
                                if (q < CAP) dst[q] = (unsigned)(idx * 8 + h * 2 + 1);
                            }
                        }
                    }
                }
            }
        } else {
            const f32x4* p = (const f32x4*)((const float*)A + (size_t)row * NN);
            #pragma unroll
            for (int c0 = 0; c0 < 24; c0 += 6) {
                f32x4 v[6];
                #pragma unroll
                for (int u = 0; u < 6; u++) {
                    int idx = (c0 + u) * 64 + lane;
                    if (idx < 1500) v[u] = __builtin_nontemporal_load(&p[idx]);
                    else v[u] = (f32x4)(0.f);
                }
                #pragma unroll
                for (int u = 0; u < 6; u++) {
                    int idx = (c0 + u) * 64 + lane;
                    #pragma unroll
                    for (int h = 0; h < 4; h++) {
                        if (v[u][h] > 0.f) {
                            int q = atomicAdd(&cnt4[w], 1);
                            if (q < CAP) dst[q] = (unsigned)(idx * 4 + h);
                        }
                    }
                }
            }
        }
        __syncthreads();
        if (lane == 0) g_cnt[gn] = min(cnt4[w], CAP);
    } else if (phase == 1) {
        // rel_agg: one wave per node, no barriers (wave-local LDS).
        int n = pb * 4 + w;
        int which = n >= NN ? 1 : 0;
        int row = n - which * NN;
        const void* radj = in.p[6 + which];
        const void* rel  = in.p[2 + which];
        const int bfa = g_dt[6 + which], bfr = g_dt[2 + which];
        __shared__ int rl_list[4][CAPR];
        __shared__ int rl_cs[4];
        if (lane == 0) rl_cs[w] = 0;
        if (bfa) {
            const uint4* p = (const uint4*)((const unsigned short*)radj + (size_t)row * RR);
            #pragma unroll
            for (int rep = 0; rep < 2; rep++) {
                int i = rep * 64 + lane;
                if (i < 125) {
                    uint4 w4 = p[i];
                    unsigned ws4[4] = {w4.x, w4.y, w4.z, w4.w};
                    #pragma unroll
                    for (int h = 0; h < 4; h++) {
                        unsigned lo = ws4[h] & 0xFFFFu, hi = ws4[h] >> 16;
                        if (lo && !(lo & 0x8000u)) { int q = atomicAdd(&rl_cs[w], 1); if (q < CAPR) rl_list[w][q] = i * 8 + h * 2; }
                        if (hi && !(hi & 0x8000u)) { int q = atomicAdd(&rl_cs[w], 1); if (q < CAPR) rl_list[w][q] = i * 8 + h * 2 + 1; }
                    }
                }
            }
        } else {
            const float4* p = (const float4*)((const float*)radj + (size_t)row * RR);
            #pragma unroll
            for (int rep = 0; rep < 4; rep++) {
                int i = rep * 64 + lane;
                if (i < 250) {
                    float4 w4 = p[i];
                    float vs[4] = {w4.x, w4.y, w4.z, w4.w};
                    #pragma unroll
                    for (int h = 0; h < 4; h++)
                        if (vs[h] > 0.f) { int q = atomicAdd(&rl_cs[w], 1); if (q < CAPR) rl_list[w][q] = i * 4 + h; }
                }
            }
        }
        int c = min(rl_cs[w], CAPR);
        float a0 = 0.f, a1 = 0.f;
        for (int j = 0; j < c; j++) {
            int li = rl_list[w][j];
            a0 += ldin(rel, (size_t)li * DD + lane, bfr);
            a1 += ldin(rel, (size_t)li * DD + 64 + lane, bfr);
        }
        float r0 = c ? a0 / (float)c : 0.f;
        float r1 = c ? a1 / (float)c : 0.f;
        out[(size_t)n * 256 + 128 + lane] = r0;
        out[(size_t)n * 256 + 192 + lane] = r1;
        out[(size_t)(2 * NN + n) * 256 + 128 + lane] = r0;
        out[(size_t)(2 * NN + n) * 256 + 192 + lane] = r1;
    } else if (phase == 2) {
        // ent_init: one wave per node, barrier-free.
        int n = pb * 4 + w;
        int which = n >= NN ? 1 : 0;
        int row = n - which * NN;
        __shared__ float us[4][128];
        float y0, y1, y2v;
        bias_wave(in.p[18], 0, lane, y0, y1, y2v);
        float x0 = ldin(in.p[which], (size_t)row * DD + lane, g_dt[which]);
        float x1 = ldin(in.p[which], (size_t)row * DD + 64 + lane, g_dt[which]);
        g_seq[(size_t)n * 384 + lane] = x0;
        g_seq[(size_t)n * 384 + 64 + lane] = x1;
        g_seqb[(size_t)n * DD + lane] = f2b(x0);          // plane 0
        g_seqb[(size_t)n * DD + 64 + lane] = f2b(x1);
        float ss = wsum(x0 * x0 + x1 * x1);
        float nrm = fmaxf(sqrtf(ss), 1e-15f);
        float t = tanhf(nrm);
        float scale = t / nrm;
        float hn = t;
        if (t > MAXN_F) { scale *= MAXN_F / t; hn = MAXN_F; }
        float lgx = atanhf(fminf(hn, 1.f - 1e-7f)) / fmaxf(hn, 1e-15f);
        us[w][lane] = lgx * scale * x0;
        us[w][64 + lane] = lgx * scale * x1;
        float o0, o1;
        hgc_lin_w(us[w], 0, lane, y0, y1, y2v, o0, o1);
        g_t[(size_t)n * DD + lane] = o0;
        g_t[(size_t)n * DD + 64 + lane] = o1;
    } else {
        int stride = 128 * 256;
        int base = pb * 256 + tid;
        const int b8 = g_dt[8], b11 = g_dt[11], b12 = g_dt[12], b13 = g_dt[13],
                  b14 = g_dt[14];
        for (int i = base; i < 65536; i += stride) {
            int e = i & 127, d = (i >> 7) & 127, h = (i >> 14) & 1, l = (i >> 15) & 1;
            g_WgatT[l][(h * 128 + e) * DD + d] = f2b(ldin(in.p[8], i, b8));
        }
        for (int i = base; i < 32768; i += stride) {
            int d = i >> 8, e = i & 255;
            g_WqkvT[(size_t)e * DD + d]         = f2b(ldin(in.p[11], i, b11));
            g_WqkvT[(size_t)(256 + e) * DD + d] = f2b(ldin(in.p[12], i, b12));
            g_WqkvT[(size_t)(512 + e) * DD + d] = f2b(ldin(in.p[13], i, b13));
        }
        for (int i = base; i < 32768; i += stride) {
            int e = i >> 7, dd = i & 127;
            g_WfcT[dd * 256 + e] = f2b(ldin(in.p[14], i, b14));
        }
    }
}

// ---------------- GAT GEMM + scores: 750 slim blocks, no GEMM LDS ----------------
// Block = 16 rows x 256 cols, K=128. A-frags direct from global (4KB/tile, L1-hot,
// 4x wave reuse); B-frags from L2-hot g_WgatT (64KB shared by all blocks).
// Wave w owns cols w*64..w*64+63; epilogue: 512B LDS + 1 barrier for es/ed.
__global__ __launch_bounds__(256) void gemm_scores(P19 in, int layer) {
    int tid = threadIdx.x;
    int w = tid >> 6, lane = tid & 63;
    int q = lane >> 4, ln = lane & 15;
    int bm = blockIdx.x * 16;
    const unsigned short* A = g_seqb + (size_t)layer * (N2 * DD);
    const unsigned short* Bt = g_WgatT[layer];
    int colbase = w * 64;
    f32x4 acc[4] = {};
    #pragma unroll
    for (int s = 0; s < 4; s++) {
        int kc = s * 4 + q;
        bf16x8 af = *(const bf16x8*)(A + (size_t)(bm + ln) * DD + kc * 8);
        #pragma unroll
        for (int nt = 0; nt < 4; nt++) {
            bf16x8 bf = *(const bf16x8*)(Bt + (size_t)(colbase + nt * 16 + ln) * DD + kc * 8);
            acc[nt] = __builtin_amdgcn_mfma_f32_16x16x32_bf16(af, bf, acc[nt], 0, 0, 0);
        }
    }
    // hhb write
    #pragma unroll
    for (int nt = 0; nt < 4; nt++) {
        int col = colbase + nt * 16 + ln;
        #pragma unroll
        for (int r = 0; r < 4; r++) {
            int row = bm + q * 4 + r;
            g_hhb[(size_t)row * 256 + col] = f2b(acc[nt][r]);
        }
    }
    // scores epilogue
    const int bfs = g_dt[9], bfd = g_dt[10];
    float a_s[4], a_d[4];
    #pragma unroll
    for (int nt = 0; nt < 4; nt++) {
        int col = colbase + nt * 16 + ln;
        size_t ab = ((size_t)layer * 2 + (col >> 7)) * DD + (col & 127);
        a_s[nt] = ldin(in.p[9],  ab, bfs);
        a_d[nt] = ldin(in.p[10], ab, bfd);
    }
    __shared__ float pS[4][16], pD[4][16];
    #pragma unroll
    for (int r = 0; r < 4; r++) {
        float ps = 0.f, pd = 0.f;
        #pragma unroll
        for (int nt = 0; nt < 4; nt++) {
            ps = fmaf(acc[nt][r], a_s[nt], ps);
            pd = fmaf(acc[nt][r], a_d[nt], pd);
        }
        #pragma unroll
        for (int o = 1; o < 16; o <<= 1) {
            ps += __shfl_xor(ps, o, 64);
            pd += __shfl_xor(pd, o, 64);
        }
        if (ln == 0) { pS[w][q * 4 + r] = ps; pD[w][q * 4 + r] = pd; }
    }
    __syncthreads();
    if (tid < 16) {
        g_es[0][bm + tid] = pS[0][tid] + pS[1][tid];
        g_es[1][bm + tid] = pS[2][tid] + pS[3][tid];
        g_ed[0][bm + tid] = pD[0][tid] + pD[1][tid];
        g_ed[1][bm + tid] = pD[2][tid] + pD[3][tid];
    }
}

// ---------------- qkv GEMM (plane-mapped A rows) ----------------
__global__ __launch_bounds__(256) void gemm_qkv() {
    __shared__ __align__(16) unsigned short As[16 * 128 * 8];
    __shared__ __align__(16) unsigned short Bs[16 * 128 * 8];
    int bm = blockIdx.y * 128, bn = blockIdx.x * 128;
    int tid = threadIdx.x;
    int lane = tid & 63, w = tid >> 6;
    int q = lane >> 4, ln = lane & 15;
    const int M = N2 * 3;
    f32x4 acc[8][2] = {};
    #pragma unroll
    for (int i = 0; i < 8; i++) {
        int combo = w * 8 + i;
        int c = combo >> 1, half = combo & 1;
        int r = half * 64 + lane;
        int gm = bm + r; if (gm >= M) gm = M - 1;
        int n = gm / 3, l = gm - n * 3;
        *(uint4*)&As[(c * 128 + r) * 8] =
            *(const uint4*)(g_seqb + (size_t)l * (N2 * DD) + (size_t)n * DD + c * 8);
        *(uint4*)&Bs[(c * 128 + r) * 8] =
            *(const uint4*)(g_WqkvT + (size_t)(bn + r) * DD + c * 8);
    }
    __syncthreads();
    #pragma unroll
    for (int s = 0; s < 4; s++) {
        bf16x8 bf0 = *(const bf16x8*)&Bs[((s * 4 + q) * 128 + w * 32 + ln) * 8];
        bf16x8 bf1 = *(const bf16x8*)&Bs[((s * 4 + q) * 128 + w * 32 + 16 + ln) * 8];
        #pragma unroll
        for (int mt = 0; mt < 8; mt++) {
            bf16x8 af = *(const bf16x8*)&As[((s * 4 + q) * 128 + mt * 16 + ln) * 8];
            acc[mt][0] = __builtin_amdgcn_mfma_f32_16x16x32_bf16(af, bf0, acc[mt][0], 0, 0, 0);
            acc[mt][1] = __builtin_amdgcn_mfma_f32_16x16x32_bf16(af, bf1, acc[mt][1], 0, 0, 0);
        }
    }
    #pragma unroll
    for (int mt = 0; mt < 8; mt++) {
        #pragma unroll
        for (int nt = 0; nt < 2; nt++) {
            int gcol = bn + w * 32 + nt * 16 + ln;
            #pragma unroll
            for (int r = 0; r < 4; r++) {
                int grow = bm + mt * 16 + q * 4 + r;
                if (grow < M)
                    g_qkvb[(size_t)grow * 768 + gcol] = f2b(acc[mt][nt][r]);
            }
        }
    }
}

// ---------------- fc GEMM (f32 out) ----------------
__global__ __launch_bounds__(256) void gemm_fc() {
    __shared__ __align__(16) unsigned short As[16 * 128 * 8];
    __shared__ __align__(16) unsigned short Bs[16 * 128 * 8];
    int bm = blockIdx.x * 128;
    int tid = threadIdx.x;
    int lane = tid & 63, w = tid >> 6;
    int q = lane >> 4, ln = lane & 15;
    const int M = N2 * 3;
    f32x4 acc[8][2] = {};
    for (int k0 = 0; k0 < 256; k0 += 128) {
        if (k0 > 0) __syncthreads();
        #pragma unroll
        for (int i = 0; i < 8; i++) {
            int combo = w * 8 + i;
            int c = combo >> 1, half = combo & 1;
            int r = half * 64 + lane;
            int gm = bm + r; if (gm >= M) gm = M - 1;
            *(uint4*)&As[(c * 128 + r) * 8] =
                *(const uint4*)(g_ob + (size_t)gm * 256 + k0 + c * 8);
            *(uint4*)&Bs[(c * 128 + r) * 8] =
                *(const uint4*)(g_WfcT + (size_t)r * 256 + k0 + c * 8);
        }
        __syncthreads();
        #pragma unroll
        for (int s = 0; s < 4; s++) {
            bf16x8 bf0 = *(const bf16x8*)&Bs[((s * 4 + q) * 128 + w * 32 + ln) * 8];
            bf16x8 bf1 = *(const bf16x8*)&Bs[((s * 4 + q) * 128 + w * 32 + 16 + ln) * 8];
            #pragma unroll
            for (int mt = 0; mt < 8; mt++) {
                bf16x8 af = *(const bf16x8*)&As[((s * 4 + q) * 128 + mt * 16 + ln) * 8];
                acc[mt][0] = __builtin_amdgcn_mfma_f32_16x16x32_bf16(af, bf0, acc[mt][0], 0, 0, 0);
                acc[mt][1] = __builtin_amdgcn_mfma_f32_16x16x32_bf16(af, bf1, acc[mt][1], 0, 0, 0);
            }
        }
    }
    #pragma unroll
    for (int mt = 0; mt < 8; mt++) {
        #pragma unroll
        for (int nt = 0; nt < 2; nt++) {
            int gcol = w * 32 + nt * 16 + ln;
            #pragma unroll
            for (int r = 0; r < 4; r++) {
                int grow = bm + mt * 16 + q * 4 + r;
                if (grow < M)
                    g_fc[(size_t)grow * 128 + gcol] = acc[mt][nt][r];
            }
        }
    }
}

// ---------------- GAT attention: wave-per-node, zero barriers ----------------
__global__ __launch_bounds__(256) void gat_attn(int layer) {
    int tid = threadIdx.x;
    int w = tid >> 6, lane = tid & 63;
    int n = blockIdx.x * 4 + w;
    int which = n >= NN ? 1 : 0;
    int c = min(g_cnt[n], CAP);
    __shared__ unsigned bas[4][CAP];
    __shared__ float w0s[4][CAP], w1s[4][CAP];
    float es0 = g_es[0][n], es1 = g_es[1][n];
    float e0a = -1e30f, e1a = -1e30f, e0b = -1e30f, e1b = -1e30f;
    if (lane < c) {
        int gI = (int)g_csri[(size_t)n * CAP + lane] + which * NN;
        bas[w][lane] = (unsigned)gI * 128u;
        e0a = es0 + g_ed[0][gI]; e0a = e0a > 0.f ? e0a : 0.2f * e0a;
        e1a = es1 + g_ed[1][gI]; e1a = e1a > 0.f ? e1a : 0.2f * e1a;
    }
    if (64 + lane < c) {
        int gI = (int)g_csri[(size_t)n * CAP + 64 + lane] + which * NN;
        bas[w][64 + lane] = (unsigned)gI * 128u;
        e0b = es0 + g_ed[0][gI]; e0b = e0b > 0.f ? e0b : 0.2f * e0b;
        e1b = es1 + g_ed[1][gI]; e1b = e1b > 0.f ? e1b : 0.2f * e1b;
    }
    float m0 = wmax(fmaxf(e0a, e0b));
    float m1 = wmax(fmaxf(e1a, e1b));
    float x0a = (lane < c) ? expf(e0a - m0) : 0.f;
    float x1a = (lane < c) ? expf(e1a - m1) : 0.f;
    float x0b = (64 + lane < c) ? expf(e0b - m0) : 0.f;
    float x1b = (64 + lane < c) ? expf(e1b - m1) : 0.f;
    float s0 = wsum(x0a + x0b), s1 = wsum(x1a + x1b);
    float r0 = 1.f / fmaxf(s0, 1e-30f), r1 = 1.f / fmaxf(s1, 1e-30f);
    if (lane < c)      { w0s[w][lane] = x0a * r0;      w1s[w][lane] = x1a * r1; }
    if (64 + lane < c) { w0s[w][64 + lane] = x0b * r0; w1s[w][64 + lane] = x1b * r1; }
    const unsigned* hh32 = (const unsigned*)g_hhb;
    float aLe = 0.f, aLo = 0.f, aHe = 0.f, aHo = 0.f;
    #pragma unroll 4
    for (int j = 0; j < c; j++) {
        unsigned bb = bas[w][j];
        unsigned vlo = hh32[(size_t)bb + lane];
        unsigned vhi = hh32[(size_t)bb + 64 + lane];
        float g0 = w0s[w][j], g1 = w1s[w][j];
        aLe = fmaf(g0, b2f((unsigned short)(vlo & 0xFFFFu)), aLe);
        aLo = fmaf(g0, b2f((unsigned short)(vlo >> 16)), aLo);
        aHe = fmaf(g1, b2f((unsigned short)(vhi & 0xFFFFu)), aHe);
        aHo = fmaf(g1, b2f((unsigned short)(vhi >> 16)), aHo);
    }
    float o0 = (c > 0) ? 0.5f * (aLe + aHe) : 0.f;
    float o1 = (c > 0) ? 0.5f * (aLo + aHo) : 0.f;
    o0 = o0 > 0.f ? o0 : expm1f(o0);
    o1 = o1 > 0.f ? o1 : expm1f(o1);
    float ss = wsum(o0 * o0 + o1 * o1);
    float rn = 1.f / fmaxf(sqrtf(ss), 1e-12f);
    o0 *= rn; o1 *= rn;
    g_seq[(size_t)n * 384 + (layer + 1) * 128 + 2 * lane] = o0;
    g_seq[(size_t)n * 384 + (layer + 1) * 128 + 2 * lane + 1] = o1;
    size_t pbase = (size_t)(layer + 1) * (N2 * DD) + (size_t)n * DD + 2 * lane;
    *(unsigned*)&g_seqb[pbase] = (unsigned)f2b(o0) | ((unsigned)f2b(o1) << 16);
}

// ---------------- combined: MHA attention (wave-per-node, reg-only) ∥ hgc_mid ----------
__global__ __launch_bounds__(256) void attn_mid(const void* __restrict__ hgc_b) {
    int tid = threadIdx.x;
    int w = tid >> 6, lane = tid & 63;
    if (blockIdx.x < 3000) {
        int n = blockIdx.x * 4 + w;
        int d0 = lane * 4;
        const unsigned short* row = g_qkvb + (size_t)n * 2304;
        float qf[3][4], kf[3][4], vf[3][4];
        #pragma unroll
        for (int l = 0; l < 3; l++) {
            uint2 qv = *(const uint2*)(row + l * 768 + d0);
            uint2 kv = *(const uint2*)(row + l * 768 + 256 + d0);
            uint2 vv = *(const uint2*)(row + l * 768 + 512 + d0);
            qf[l][0] = b2f((unsigned short)(qv.x & 0xFFFFu)); qf[l][1] = b2f((unsigned short)(qv.x >> 16));
            qf[l][2] = b2f((unsigned short)(qv.y & 0xFFFFu)); qf[l][3] = b2f((unsigned short)(qv.y >> 16));
            kf[l][0] = b2f((unsigned short)(kv.x & 0xFFFFu)); kf[l][1] = b2f((unsigned short)(kv.x >> 16));
            kf[l][2] = b2f((unsigned short)(kv.y & 0xFFFFu)); kf[l][3] = b2f((unsigned short)(kv.y >> 16));
            vf[l][0] = b2f((unsigned short)(vv.x & 0xFFFFu)); vf[l][1] = b2f((unsigned short)(vv.x >> 16));
            vf[l][2] = b2f((unsigned short)(vv.y & 0xFFFFu)); vf[l][3] = b2f((unsigned short)(vv.y >> 16));
        }
        float att[3][3];
        #pragma unroll
        for (int l = 0; l < 3; l++) {
            #pragma unroll
            for (int m = 0; m < 3; m++) {
                float p = 0.f;
                #pragma unroll
                for (int i = 0; i < 4; i++) p = fmaf(qf[l][i], kf[m][i], p);
                #pragma unroll
                for (int o = 16; o > 0; o >>= 1) p += __shfl_xor(p, o, 64);
                att[l][m] = p * 0.08838834764831845f;
            }
        }
        #pragma unroll
        for (int l = 0; l < 3; l++) {
            float mx = fmaxf(att[l][0], fmaxf(att[l][1], att[l][2]));
            float e0 = expf(att[l][0] - mx), e1 = expf(att[l][1] - mx), e2 = expf(att[l][2] - mx);
            float s = 1.f / fmaxf(e0 + e1 + e2, 1e-30f);
            att[l][0] = e0 * s; att[l][1] = e1 * s; att[l][2] = e2 * s;
        }
        unsigned short* orow = g_ob + (size_t)n * 768;
        #pragma unroll
        for (int l = 0; l < 3; l++) {
            float o[4];
            #pragma unroll
            for (int i = 0; i < 4; i++)
                o[i] = att[l][0] * vf[0][i] + att[l][1] * vf[1][i] + att[l][2] * vf[2][i];
            uint2 pk;
            pk.x = (unsigned)f2b(o[0]) | ((unsigned)f2b(o[1]) << 16);
            pk.y = (unsigned)f2b(o[2]) | ((unsigned)f2b(o[3]) << 16);
            *(uint2*)(orow + l * 256 + d0) = pk;
        }
    } else {
        int n = (blockIdx.x - 3000) * 4 + w;
        int which = n >= NN ? 1 : 0;
        __shared__ unsigned bas[4][CAP];
        __shared__ float us[4][128];
        float y0, y1, y2v;
        bias_wave(hgc_b, 1, lane, y0, y1, y2v);
        float u0, u1;
        hgc_agg_w(g_t, n, which, lane, bas[w], u0, u1);
        us[w][lane] = u0; us[w][64 + lane] = u1;
        float o0, o1;
        hgc_lin_w(us[w], 1, lane, y0, y1, y2v, o0, o1);
        g_t2[(size_t)n * DD + lane] = o0;
        g_t2[(size_t)n * DD + 64 + lane] = o1;
    }
}

// ---------------- combined: mha_out ∥ hgc_fin (all wave-per-node) ----------------
__global__ __launch_bounds__(256) void out_fin(const void* __restrict__ g, const void* __restrict__ b,
                                               const void* __restrict__ e0, const void* __restrict__ e1,
                                               float* __restrict__ out) {
    int tid = threadIdx.x;
    int w = tid >> 6, lane = tid & 63;
    if (blockIdx.x < 3000) {
        int n = blockIdx.x * 4 + w;
        const int bg = g_dt[15], bb = g_dt[16];
        float ool0[3], ool1[3], mu[3], rstd[3];
        #pragma unroll
        for (int l = 0; l < 3; l++) {
            ool0[l] = g_fc[(size_t)(n * 3 + l) * 128 + lane] + g_seq[(size_t)(n * 3 + l) * 128 + lane];
            ool1[l] = g_fc[(size_t)(n * 3 + l) * 128 + 64 + lane] + g_seq[(size_t)(n * 3 + l) * 128 + 64 + lane];
        }
        #pragma unroll
        for (int l = 0; l < 3; l++) {
            float s  = wsum(ool0[l] + ool1[l]);
            float ss = wsum(ool0[l] * ool0[l] + ool1[l] * ool1[l]);
            mu[l] = s / 128.f;
            rstd[l] = rsqrtf(ss / 128.f - mu[l] * mu[l] + 1e-6f);
        }
        float acc0 = 0.f, acc1 = 0.f;
        #pragma unroll
        for (int l = 0; l < 3; l++) {
            acc0 += (ool0[l] - mu[l]) * rstd[l];
            acc1 += (ool1[l] - mu[l]) * rstd[l];
        }
        out[(size_t)n * 256 + lane]      = ldin(g, lane, bg) * (acc0 / 3.f) + ldin(b, lane, bb);
        out[(size_t)n * 256 + 64 + lane] = ldin(g, 64 + lane, bg) * (acc1 / 3.f) + ldin(b, 64 + lane, bb);
    } else {
        int n = (blockIdx.x - 3000) * 4 + w;
        int which = n >= NN ? 1 : 0;
        __shared__ unsigned bas[4][CAP];
        float u0, u1;
        hgc_agg_w(g_t2, n, which, lane, bas[w], u0, u1);
        float ev0 = ldin(which ? e1 : e0, (size_t)(n - which * NN) * DD + lane, g_dt[which]);
        float ev1 = ldin(which ? e1 : e0, (size_t)(n - which * NN) * DD + 64 + lane, g_dt[which]);
        out[(size_t)(2 * NN + n) * 256 + lane]      = ev0 + u0;
        out[(size_t)(2 * NN + n) * 256 + 64 + lane] = ev1 + u1;
    }
}

extern "C" void kernel_launch(void* const* d_in, const int* in_sizes, int n_in,
                              void* d_out, int out_size, void* d_ws, size_t ws_size,
                              hipStream_t stream) {
    const void* ln_g = d_in[15];
    const void* ln_b = d_in[16];
    const void* hgc_b = d_in[18];

    float* out = (float*)d_out;

    P19 ptrs;
    for (int i = 0; i < 19; i++) ptrs.p[i] = d_in[i];
    detect_all<<<20, 1024, 0, stream>>>(ptrs);

    front_mega<<<9128, 256, 0, stream>>>(ptrs, out);

    gemm_scores<<<750, 256, 0, stream>>>(ptrs, 0);
    gat_attn<<<3000, 256, 0, stream>>>(0);
    gemm_scores<<<750, 256, 0, stream>>>(ptrs, 1);
    gat_attn<<<3000, 256, 0, stream>>>(1);

    gemm_qkv<<<dim3(6, 282), 256, 0, stream>>>();
    attn_mid<<<6000, 256, 0, stream>>>(hgc_b);
    gemm_fc<<<282, 256, 0, stream>>>();
    out_fin<<<6000, 256, 0, stream>>>(ln_g, ln_b, d_in[0], d_in[1], out);
}